// Round 1
// baseline (16328.522 us; speedup 1.0000x reference)
//
#include <hip/hip_runtime.h>

#define N_NODES 100000
#define N_EDGES 3200000
#define FEAT 256
#define HID 128
#define OUT 64
#define HOPS 3

// ---------------- input GEMM: curr = X @ W + b ; feat = w0 * curr ----------
// block = 128 threads (one thread per HID column), 16 rows per block.
__global__ __launch_bounds__(128) void gemm_in(
    const float* __restrict__ X,      // [N, FEAT]
    const float* __restrict__ W,      // [FEAT, HID]
    const float* __restrict__ b,      // [HID]
    const float* __restrict__ wvec,   // hop scales, use wvec[0]
    float* __restrict__ curr,         // [N, HID]
    float* __restrict__ feat)         // [N, HID]
{
    __shared__ float xs[16][FEAT];
    const int base = blockIdx.x * 16;
    const int tid = threadIdx.x;

    for (int idx = tid; idx < 16 * FEAT; idx += 128) {
        int r = idx >> 8;        // / FEAT
        int k = idx & (FEAT - 1);
        int row = base + r;
        xs[r][k] = (row < N_NODES) ? X[(size_t)row * FEAT + k] : 0.f;
    }
    __syncthreads();

    float acc[16];
#pragma unroll
    for (int r = 0; r < 16; ++r) acc[r] = 0.f;

    const int j = tid;
    for (int k = 0; k < FEAT; ++k) {
        float w = W[k * HID + j];
#pragma unroll
        for (int r = 0; r < 16; ++r) acc[r] += xs[r][k] * w;
    }

    const float bj = b[j];
    const float s0 = wvec[0];
#pragma unroll
    for (int r = 0; r < 16; ++r) {
        int row = base + r;
        if (row < N_NODES) {
            float v = acc[r] + bj;
            curr[(size_t)row * HID + j] = v;
            feat[(size_t)row * HID + j] = s0 * v;
        }
    }
}

// ---------------- SPMM: out[dst[e]] += w[e] * x[src[e]]  (atomic scatter) ---
// one wave (64 lanes) per edge; each lane handles 2 consecutive floats.
__global__ __launch_bounds__(256) void spmm_atomic(
    const int* __restrict__ dst,
    const int* __restrict__ src,
    const float* __restrict__ ew,
    const float* __restrict__ x,      // [N, HID]
    float* __restrict__ out)          // [N, HID], pre-zeroed
{
    long long gid = (long long)blockIdx.x * 256 + threadIdx.x;
    int e = (int)(gid >> 6);
    int lane = (int)(gid & 63);
    if (e >= N_EDGES) return;

    int d = dst[e];
    int s = src[e];
    float wt = ew[e];

    float2 v = ((const float2*)(x + (size_t)s * HID))[lane];
    float* op = out + (size_t)d * HID + lane * 2;
    unsafeAtomicAdd(op, v.x * wt);
    unsafeAtomicAdd(op + 1, v.y * wt);
}

// ---------------- axpy: y += wvec[h] * x ----------------------------------
__global__ __launch_bounds__(256) void axpy_k(
    const float* __restrict__ x,
    const float* __restrict__ wvec, int h,
    float* __restrict__ y)
{
    const float a = wvec[h];
    size_t i = (size_t)blockIdx.x * 256 + threadIdx.x;
    const size_t n4 = (size_t)N_NODES * HID / 4;
    if (i < n4) {
        float4 xv = ((const float4*)x)[i];
        float4 yv = ((float4*)y)[i];
        yv.x += a * xv.x;
        yv.y += a * xv.y;
        yv.z += a * xv.z;
        yv.w += a * xv.w;
        ((float4*)y)[i] = yv;
    }
}

// ---------------- output GEMM: out = [feat_s | feat_t] @ Wn + bn ------------
// block = 64 threads (one per OUT column), 32 rows per block.
__global__ __launch_bounds__(64) void gemm_out(
    const float* __restrict__ fs,     // [N, HID]
    const float* __restrict__ ft,     // [N, HID]
    const float* __restrict__ Wn,     // [2*HID, OUT]
    const float* __restrict__ bn,     // [OUT]
    float* __restrict__ out)          // [N, OUT]
{
    __shared__ float xs[32][2 * HID];
    const int base = blockIdx.x * 32;
    const int tid = threadIdx.x;

    for (int idx = tid; idx < 32 * HID; idx += 64) {
        int r = idx >> 7;        // / HID
        int k = idx & (HID - 1);
        int row = base + r;
        float a = 0.f, c = 0.f;
        if (row < N_NODES) {
            a = fs[(size_t)row * HID + k];
            c = ft[(size_t)row * HID + k];
        }
        xs[r][k] = a;
        xs[r][k + HID] = c;
    }
    __syncthreads();

    float acc[32];
#pragma unroll
    for (int r = 0; r < 32; ++r) acc[r] = 0.f;

    const int j = tid;
    for (int k = 0; k < 2 * HID; ++k) {
        float w = Wn[k * OUT + j];
#pragma unroll
        for (int r = 0; r < 32; ++r) acc[r] += xs[r][k] * w;
    }

    const float bj = bn[j];
#pragma unroll
    for (int r = 0; r < 32; ++r) {
        int row = base + r;
        if (row < N_NODES)
            out[(size_t)row * OUT + j] = acc[r] + bj;
    }
}

extern "C" void kernel_launch(void* const* d_in, const int* in_sizes, int n_in,
                              void* d_out, int out_size, void* d_ws, size_t ws_size,
                              hipStream_t stream) {
    const float* fsrc = (const float*)d_in[0];
    const float* ftgt = (const float*)d_in[1];
    const int*   erow = (const int*)d_in[2];
    const int*   ecol = (const int*)d_in[3];
    const float* ew   = (const float*)d_in[4];
    const float* Wsrc = (const float*)d_in[5];
    const float* bsrc = (const float*)d_in[6];
    const float* Wtgt = (const float*)d_in[7];
    const float* btgt = (const float*)d_in[8];
    const float* ws   = (const float*)d_in[9];
    const float* wt   = (const float*)d_in[10];
    const float* Wn   = (const float*)d_in[11];
    const float* bn   = (const float*)d_in[12];
    float* out = (float*)d_out;

    const size_t buf = (size_t)N_NODES * HID;  // floats per node-feature buffer
    float* p = (float*)d_ws;
    float* curr_s = p; p += buf;
    float* curr_t = p; p += buf;
    float* next_s = p; p += buf;
    float* next_t = p; p += buf;
    float* feat_s = p; p += buf;
    float* feat_t = p; p += buf;

    // input GEMMs (+ fused feat init with hop-0 scale)
    dim3 g1((N_NODES + 15) / 16);
    gemm_in<<<g1, 128, 0, stream>>>(fsrc, Wsrc, bsrc, ws, curr_s, feat_s);
    gemm_in<<<g1, 128, 0, stream>>>(ftgt, Wtgt, btgt, wt, curr_t, feat_t);

    const long long total_thr = (long long)N_EDGES * 64;
    const int spmm_blocks = (int)((total_thr + 255) / 256);
    const int axpy_blocks = (int)((buf / 4 + 255) / 256);

    for (int h = 1; h <= HOPS; ++h) {
        hipMemsetAsync(next_s, 0, buf * sizeof(float), stream);
        hipMemsetAsync(next_t, 0, buf * sizeof(float), stream);
        // curr_s = adj @ curr_s : dst=row, src=col
        spmm_atomic<<<spmm_blocks, 256, 0, stream>>>(erow, ecol, ew, curr_s, next_s);
        // curr_t = adj^T @ curr_t : dst=col, src=row
        spmm_atomic<<<spmm_blocks, 256, 0, stream>>>(ecol, erow, ew, curr_t, next_t);
        axpy_k<<<axpy_blocks, 256, 0, stream>>>(next_s, ws, h, feat_s);
        axpy_k<<<axpy_blocks, 256, 0, stream>>>(next_t, wt, h, feat_t);
        float* t;
        t = curr_s; curr_s = next_s; next_s = t;
        t = curr_t; curr_t = next_t; next_t = t;
    }

    gemm_out<<<(N_NODES + 31) / 32, 64, 0, stream>>>(feat_s, feat_t, Wn, bn, out);
}

// Round 2
// 2587.116 us; speedup vs baseline: 6.3115x; 6.3115x over previous
//
#include <hip/hip_runtime.h>

#define N_NODES 100000
#define N_EDGES 3200000
#define FEAT 256
#define HID 128
#define OUT 64
#define HOPS 3

#define CHUNK 1024                       // elements scanned per block (256 thr x 4)
#define NCHUNK ((N_NODES + CHUNK - 1) / CHUNK)   // 98
#define NPAD (NCHUNK * CHUNK)            // 100352

// ---------------- CSR build: histogram ------------------------------------
__global__ __launch_bounds__(256) void hist_k(
    const int* __restrict__ dst, int* __restrict__ cnt)
{
    int e = blockIdx.x * 256 + threadIdx.x;
    if (e < N_EDGES) atomicAdd(&cnt[dst[e]], 1);
}

// ---------------- CSR build: hierarchical exclusive scan -------------------
__global__ __launch_bounds__(256) void scan1_k(
    const int* __restrict__ cnt, int* __restrict__ local, int* __restrict__ chunksum)
{
    __shared__ int sdata[256];
    const int tid = threadIdx.x;
    const int base = blockIdx.x * CHUNK;

    int4 v = ((const int4*)(cnt + base))[tid];
    int tsum = v.x + v.y + v.z + v.w;
    sdata[tid] = tsum;
    __syncthreads();
    for (int off = 1; off < 256; off <<= 1) {
        int t = (tid >= off) ? sdata[tid - off] : 0;
        __syncthreads();
        sdata[tid] += t;
        __syncthreads();
    }
    int excl = sdata[tid] - tsum;
    int4 o;
    o.x = excl;
    o.y = excl + v.x;
    o.z = o.y + v.y;
    o.w = o.z + v.z;
    ((int4*)(local + base))[tid] = o;
    if (tid == 255) chunksum[blockIdx.x] = sdata[255];
}

__global__ __launch_bounds__(128) void scan2_k(
    const int* __restrict__ chunksum, int* __restrict__ chunkoff, int* __restrict__ rowptr)
{
    __shared__ int sdata[128];
    const int tid = threadIdx.x;
    int v = (tid < NCHUNK) ? chunksum[tid] : 0;
    sdata[tid] = v;
    __syncthreads();
    for (int off = 1; off < 128; off <<= 1) {
        int t = (tid >= off) ? sdata[tid - off] : 0;
        __syncthreads();
        sdata[tid] += t;
        __syncthreads();
    }
    int excl = sdata[tid] - v;
    if (tid < NCHUNK) chunkoff[tid] = excl;
    if (tid == NCHUNK - 1) rowptr[N_NODES] = excl + v;   // total edges
}

__global__ __launch_bounds__(256) void scan3_k(
    const int* __restrict__ local, const int* __restrict__ chunkoff,
    int* __restrict__ rowptr)
{
    const int off = chunkoff[blockIdx.x];
    const int base = blockIdx.x * CHUNK + threadIdx.x * 4;
#pragma unroll
    for (int j = 0; j < 4; ++j) {
        int i = base + j;
        if (i < N_NODES) rowptr[i] = local[i] + off;
    }
}

// ---------------- CSR build: scatter edges into sorted order ---------------
__global__ __launch_bounds__(256) void fill_k(
    const int* __restrict__ dst, const int* __restrict__ src,
    const float* __restrict__ ew,
    const int* __restrict__ rowptr, int* __restrict__ cursor,
    int2* __restrict__ meta)
{
    int e = blockIdx.x * 256 + threadIdx.x;
    if (e >= N_EDGES) return;
    int d = dst[e];
    int pos = rowptr[d] + atomicAdd(&cursor[d], 1);
    meta[pos] = make_int2(src[e], __float_as_int(ew[e]));
}

// ---------------- input GEMM: curr = X @ W + b ; feat = w0 * curr ----------
__global__ __launch_bounds__(128) void gemm_in(
    const float* __restrict__ X,      // [N, FEAT]
    const float* __restrict__ W,      // [FEAT, HID]
    const float* __restrict__ b,      // [HID]
    const float* __restrict__ wvec,   // hop scales, use wvec[0]
    float* __restrict__ curr,         // [N, HID]
    float* __restrict__ feat)         // [N, HID]
{
    __shared__ float xs[16][FEAT];
    const int base = blockIdx.x * 16;
    const int tid = threadIdx.x;

    for (int idx = tid; idx < 16 * FEAT; idx += 128) {
        int r = idx >> 8;
        int k = idx & (FEAT - 1);
        int row = base + r;
        xs[r][k] = (row < N_NODES) ? X[(size_t)row * FEAT + k] : 0.f;
    }
    __syncthreads();

    float acc[16];
#pragma unroll
    for (int r = 0; r < 16; ++r) acc[r] = 0.f;

    const int j = tid;
    for (int k = 0; k < FEAT; ++k) {
        float w = W[k * HID + j];
#pragma unroll
        for (int r = 0; r < 16; ++r) acc[r] += xs[r][k] * w;
    }

    const float bj = b[j];
    const float s0 = wvec[0];
#pragma unroll
    for (int r = 0; r < 16; ++r) {
        int row = base + r;
        if (row < N_NODES) {
            float v = acc[r] + bj;
            curr[(size_t)row * HID + j] = v;
            feat[(size_t)row * HID + j] = s0 * v;
        }
    }
}

// ---------------- fused CSR SPMM + axpy -------------------------------------
// one block per destination row; 128 threads = 128 columns.
// nxt[row] = sum_e w_e * x[src_e]; feat[row] += wvec[h] * nxt[row]
__global__ __launch_bounds__(128) void spmm_csr(
    const int* __restrict__ rowptr,
    const int2* __restrict__ meta,    // (src, w) sorted by dst
    const float* __restrict__ x,      // [N, HID]
    float* __restrict__ nxt,          // [N, HID]
    float* __restrict__ feat,         // [N, HID]
    const float* __restrict__ wvec, int h)
{
    __shared__ int2 smeta[128];
    const int row = blockIdx.x;
    const int tid = threadIdx.x;
    const int start = rowptr[row];
    const int end = rowptr[row + 1];

    float acc = 0.f;
    for (int t = start; t < end; t += 128) {
        int n = end - t;
        if (n > 128) n = 128;
        if (tid < n) smeta[tid] = meta[t + tid];
        __syncthreads();
#pragma unroll 4
        for (int j = 0; j < n; ++j) {
            int2 m = smeta[j];
            acc += __int_as_float(m.y) * x[(size_t)m.x * HID + tid];
        }
        __syncthreads();
    }

    const size_t o = (size_t)row * HID + tid;
    nxt[o] = acc;
    feat[o] += wvec[h] * acc;
}

// ---------------- output GEMM: out = [feat_s | feat_t] @ Wn + bn ------------
__global__ __launch_bounds__(64) void gemm_out(
    const float* __restrict__ fs,     // [N, HID]
    const float* __restrict__ ft,     // [N, HID]
    const float* __restrict__ Wn,     // [2*HID, OUT]
    const float* __restrict__ bn,     // [OUT]
    float* __restrict__ out)          // [N, OUT]
{
    __shared__ float xs[32][2 * HID];
    const int base = blockIdx.x * 32;
    const int tid = threadIdx.x;

    for (int idx = tid; idx < 32 * HID; idx += 64) {
        int r = idx >> 7;
        int k = idx & (HID - 1);
        int row = base + r;
        float a = 0.f, c = 0.f;
        if (row < N_NODES) {
            a = fs[(size_t)row * HID + k];
            c = ft[(size_t)row * HID + k];
        }
        xs[r][k] = a;
        xs[r][k + HID] = c;
    }
    __syncthreads();

    float acc[32];
#pragma unroll
    for (int r = 0; r < 32; ++r) acc[r] = 0.f;

    const int j = tid;
    for (int k = 0; k < 2 * HID; ++k) {
        float w = Wn[k * OUT + j];
#pragma unroll
        for (int r = 0; r < 32; ++r) acc[r] += xs[r][k] * w;
    }

    const float bj = bn[j];
#pragma unroll
    for (int r = 0; r < 32; ++r) {
        int row = base + r;
        if (row < N_NODES)
            out[(size_t)row * OUT + j] = acc[r] + bj;
    }
}

// ---------------------------------------------------------------------------
static void build_csr(const int* dst, const int* src, const float* ew,
                      int* rowptr, int2* meta,
                      int* cnt, int* local, int* chunksum, int* chunkoff,
                      int* cursor, hipStream_t stream)
{
    const int eb = (N_EDGES + 255) / 256;
    hipMemsetAsync(cnt, 0, NPAD * sizeof(int), stream);
    hipMemsetAsync(cursor, 0, N_NODES * sizeof(int), stream);
    hist_k<<<eb, 256, 0, stream>>>(dst, cnt);
    scan1_k<<<NCHUNK, 256, 0, stream>>>(cnt, local, chunksum);
    scan2_k<<<1, 128, 0, stream>>>(chunksum, chunkoff, rowptr);
    scan3_k<<<NCHUNK, 256, 0, stream>>>(local, chunkoff, rowptr);
    fill_k<<<eb, 256, 0, stream>>>(dst, src, ew, rowptr, cursor, meta);
}

extern "C" void kernel_launch(void* const* d_in, const int* in_sizes, int n_in,
                              void* d_out, int out_size, void* d_ws, size_t ws_size,
                              hipStream_t stream) {
    const float* fsrc = (const float*)d_in[0];
    const float* ftgt = (const float*)d_in[1];
    const int*   erow = (const int*)d_in[2];
    const int*   ecol = (const int*)d_in[3];
    const float* ew   = (const float*)d_in[4];
    const float* Wsrc = (const float*)d_in[5];
    const float* bsrc = (const float*)d_in[6];
    const float* Wtgt = (const float*)d_in[7];
    const float* btgt = (const float*)d_in[8];
    const float* ws   = (const float*)d_in[9];
    const float* wt   = (const float*)d_in[10];
    const float* Wn   = (const float*)d_in[11];
    const float* bn   = (const float*)d_in[12];
    float* out = (float*)d_out;

    const size_t buf = (size_t)N_NODES * HID;  // floats per node-feature buffer
    char* p = (char*)d_ws;
    float* curr_s = (float*)p; p += buf * 4;
    float* curr_t = (float*)p; p += buf * 4;
    float* next_s = (float*)p; p += buf * 4;
    float* next_t = (float*)p; p += buf * 4;
    float* feat_s = (float*)p; p += buf * 4;
    float* feat_t = (float*)p; p += buf * 4;
    int2* meta_s  = (int2*)p;  p += (size_t)N_EDGES * 8;
    int2* meta_t  = (int2*)p;  p += (size_t)N_EDGES * 8;
    int* rp_s     = (int*)p;   p += (NPAD + 64) * 4;
    int* rp_t     = (int*)p;   p += (NPAD + 64) * 4;
    int* cnt      = (int*)p;   p += NPAD * 4;
    int* local    = (int*)p;   p += NPAD * 4;
    int* cursor   = (int*)p;   p += NPAD * 4;
    int* chunksum = (int*)p;   p += 256 * 4;
    int* chunkoff = (int*)p;   p += 256 * 4;

    // build CSR for both directions (amortized over 3 hops each)
    build_csr(erow, ecol, ew, rp_s, meta_s, cnt, local, chunksum, chunkoff, cursor, stream);
    build_csr(ecol, erow, ew, rp_t, meta_t, cnt, local, chunksum, chunkoff, cursor, stream);

    // input GEMMs (+ fused feat init with hop-0 scale)
    dim3 g1((N_NODES + 15) / 16);
    gemm_in<<<g1, 128, 0, stream>>>(fsrc, Wsrc, bsrc, ws, curr_s, feat_s);
    gemm_in<<<g1, 128, 0, stream>>>(ftgt, Wtgt, btgt, wt, curr_t, feat_t);

    for (int h = 1; h <= HOPS; ++h) {
        spmm_csr<<<N_NODES, 128, 0, stream>>>(rp_s, meta_s, curr_s, next_s, feat_s, ws, h);
        spmm_csr<<<N_NODES, 128, 0, stream>>>(rp_t, meta_t, curr_t, next_t, feat_t, wt, h);
        float* t;
        t = curr_s; curr_s = next_s; next_s = t;
        t = curr_t; curr_t = next_t; next_t = t;
    }

    gemm_out<<<(N_NODES + 31) / 32, 64, 0, stream>>>(feat_s, feat_t, Wn, bn, out);
}

// Round 3
// 2192.905 us; speedup vs baseline: 7.4461x; 1.1798x over previous
//
#include <hip/hip_runtime.h>

#define N_NODES 100000
#define N_EDGES 3200000
#define FEAT 256
#define HID 128
#define OUT 64
#define HOPS 3

#define CHUNK 1024                                   // elements scanned per block
#define NCHUNK ((N_NODES + CHUNK - 1) / CHUNK)       // 98
#define NPAD (NCHUNK * CHUNK)                        // 100352
#define NTOT (2 * NPAD)                              // combined s|t node space
#define NCHUNK2 (NTOT / CHUNK)                       // 196

// ---------------- CSR build: histogram (both directions, one pass) ---------
__global__ __launch_bounds__(256) void hist2_k(
    const int* __restrict__ erow, const int* __restrict__ ecol,
    int* __restrict__ cnt)
{
    int e = blockIdx.x * 256 + threadIdx.x;
    if (e < N_EDGES) {
        atomicAdd(&cnt[erow[e]], 1);          // s: dst = row
        atomicAdd(&cnt[NPAD + ecol[e]], 1);   // t: dst = col
    }
}

// ---------------- hierarchical exclusive scan over NTOT --------------------
__global__ __launch_bounds__(256) void scan1_k(
    const int* __restrict__ cnt, int* __restrict__ local, int* __restrict__ chunksum)
{
    __shared__ int sdata[256];
    const int tid = threadIdx.x;
    const int base = blockIdx.x * CHUNK;

    int4 v = ((const int4*)(cnt + base))[tid];
    int tsum = v.x + v.y + v.z + v.w;
    sdata[tid] = tsum;
    __syncthreads();
    for (int off = 1; off < 256; off <<= 1) {
        int t = (tid >= off) ? sdata[tid - off] : 0;
        __syncthreads();
        sdata[tid] += t;
        __syncthreads();
    }
    int excl = sdata[tid] - tsum;
    int4 o;
    o.x = excl;
    o.y = excl + v.x;
    o.z = o.y + v.y;
    o.w = o.z + v.z;
    ((int4*)(local + base))[tid] = o;
    if (tid == 255) chunksum[blockIdx.x] = sdata[255];
}

__global__ __launch_bounds__(256) void scan2_k(
    const int* __restrict__ chunksum, int* __restrict__ chunkoff, int* __restrict__ rowptr)
{
    __shared__ int sdata[256];
    const int tid = threadIdx.x;
    int v = (tid < NCHUNK2) ? chunksum[tid] : 0;
    sdata[tid] = v;
    __syncthreads();
    for (int off = 1; off < 256; off <<= 1) {
        int t = (tid >= off) ? sdata[tid - off] : 0;
        __syncthreads();
        sdata[tid] += t;
        __syncthreads();
    }
    int excl = sdata[tid] - v;
    if (tid < NCHUNK2) chunkoff[tid] = excl;
    if (tid == NCHUNK2 - 1) rowptr[NTOT] = excl + v;   // == 2*N_EDGES
}

__global__ __launch_bounds__(256) void scan3_k(
    const int* __restrict__ local, const int* __restrict__ chunkoff,
    int* __restrict__ rowptr)
{
    const int off = chunkoff[blockIdx.x];
    const int i = blockIdx.x * CHUNK + threadIdx.x * 4;
    int4 v = *(const int4*)(local + i);
    v.x += off; v.y += off; v.z += off; v.w += off;
    *(int4*)(rowptr + i) = v;
}

// ---------------- fill both CSRs in one pass -------------------------------
__global__ __launch_bounds__(256) void fill2_k(
    const int* __restrict__ erow, const int* __restrict__ ecol,
    const float* __restrict__ ew,
    const int* __restrict__ rowptr, int* __restrict__ cursor,
    int2* __restrict__ meta)
{
    int e = blockIdx.x * 256 + threadIdx.x;
    if (e >= N_EDGES) return;
    int r = erow[e], c = ecol[e];
    int wbits = __float_as_int(ew[e]);
    int ps = rowptr[r] + atomicAdd(&cursor[r], 1);
    meta[ps] = make_int2(c, wbits);                         // s: src = col
    int pt = rowptr[NPAD + c] + atomicAdd(&cursor[NPAD + c], 1);
    meta[pt] = make_int2(r, wbits);                         // t: src = row
}

// ---------------- input GEMM: curr = X @ W + b ; feat = w0 * curr ----------
// 256 threads, 64 rows x 128 cols per block, BK=32, 32 acc/thread.
__global__ __launch_bounds__(256) void gemm_in(
    const float* __restrict__ X,      // [N, FEAT]
    const float* __restrict__ W,      // [FEAT, HID]
    const float* __restrict__ bias,   // [HID]
    const float* __restrict__ wvec,   // hop scales, use wvec[0]
    float* __restrict__ curr,         // [N, HID]
    float* __restrict__ feat)         // [N, HID]
{
    __shared__ __align__(16) float at[32][76];   // A transposed [kk][row]
    __shared__ __align__(16) float bs[32][HID];  // W chunk [kk][j]
    const int tid = threadIdx.x;
    const int tx = tid & 31;          // col group: cols tx*4 .. tx*4+3
    const int ty = tid >> 5;          // row group: rows ty*8 .. ty*8+7
    const int row0 = blockIdx.x * 64;

    float acc[8][4];
#pragma unroll
    for (int r = 0; r < 8; ++r)
#pragma unroll
        for (int c = 0; c < 4; ++c) acc[r][c] = 0.f;

    const int lc = tid & 7;           // f4 index within 32-wide K chunk
    const int lr = tid >> 3;          // 0..31

    for (int k0 = 0; k0 < FEAT; k0 += 32) {
        // stage A transposed
#pragma unroll
        for (int p = 0; p < 2; ++p) {
            int r = lr + p * 32;
            int grow = row0 + r; if (grow > N_NODES - 1) grow = N_NODES - 1;
            float4 v = *(const float4*)(X + (size_t)grow * FEAT + k0 + lc * 4);
            float vv[4] = {v.x, v.y, v.z, v.w};
#pragma unroll
            for (int i = 0; i < 4; ++i) {
                int ii = (i + lc) & 3;           // rotate to spread banks
                at[lc * 4 + ii][r] = vv[ii];
            }
        }
        // stage B
        {
            int jf = tid & 31, kk0 = tid >> 5;
#pragma unroll
            for (int p = 0; p < 4; ++p) {
                int kk = kk0 + p * 8;
                *(float4*)&bs[kk][jf * 4] =
                    *(const float4*)(W + (size_t)(k0 + kk) * HID + jf * 4);
            }
        }
        __syncthreads();
#pragma unroll 4
        for (int kk = 0; kk < 32; ++kk) {
            float4 a0 = *(const float4*)&at[kk][ty * 8];
            float4 a1 = *(const float4*)&at[kk][ty * 8 + 4];
            float4 b  = *(const float4*)&bs[kk][tx * 4];
            float av[8] = {a0.x, a0.y, a0.z, a0.w, a1.x, a1.y, a1.z, a1.w};
            float bv[4] = {b.x, b.y, b.z, b.w};
#pragma unroll
            for (int r = 0; r < 8; ++r)
#pragma unroll
                for (int c = 0; c < 4; ++c)
                    acc[r][c] = fmaf(av[r], bv[c], acc[r][c]);
        }
        __syncthreads();
    }

    const float s0 = wvec[0];
    float4 bj = *(const float4*)(bias + tx * 4);
    float bjv[4] = {bj.x, bj.y, bj.z, bj.w};
#pragma unroll
    for (int r = 0; r < 8; ++r) {
        int grow = row0 + ty * 8 + r;
        if (grow < N_NODES) {
            float o[4];
#pragma unroll
            for (int c = 0; c < 4; ++c) o[c] = acc[r][c] + bjv[c];
            size_t off = (size_t)grow * HID + tx * 4;
            *(float4*)(curr + off) = make_float4(o[0], o[1], o[2], o[3]);
            *(float4*)(feat + off) = make_float4(s0*o[0], s0*o[1], s0*o[2], s0*o[3]);
        }
    }
}

// ---------------- fused SPMM + axpy, wave-per-row, both directions ---------
// unit < NPAD: s-direction row=unit ; unit >= NPAD: t-direction row=unit-NPAD
__global__ __launch_bounds__(256) void spmm_k(
    const int* __restrict__ rowptr,
    const int2* __restrict__ meta,
    const float* __restrict__ xs, const float* __restrict__ xt,
    float* __restrict__ ns, float* __restrict__ nt,
    float* __restrict__ fs, float* __restrict__ ft,
    const float* __restrict__ wsv, const float* __restrict__ wtv,
    int h, int store_next)
{
    const int unit = blockIdx.x * 4 + (threadIdx.x >> 6);   // one wave per unit
    const int lane = threadIdx.x & 63;

    const float* x; float* nxt; float* feat; float w;
    int node;
    if (unit < NPAD) {
        node = unit;
        if (node >= N_NODES) return;
        x = xs; nxt = ns; feat = fs; w = wsv[h];
    } else {
        node = unit - NPAD;
        if (node >= N_NODES) return;
        x = xt; nxt = nt; feat = ft; w = wtv[h];
    }

    const int start = rowptr[unit];
    const int end   = rowptr[unit + 1];
    const int loff  = lane << 1;

    float ax = 0.f, ay = 0.f;
    int j = start;
    for (; j + 3 < end; j += 4) {
        int2 m0 = meta[j + 0];
        int2 m1 = meta[j + 1];
        int2 m2 = meta[j + 2];
        int2 m3 = meta[j + 3];
        float2 v0 = *(const float2*)(x + ((size_t)m0.x << 7) + loff);
        float2 v1 = *(const float2*)(x + ((size_t)m1.x << 7) + loff);
        float2 v2 = *(const float2*)(x + ((size_t)m2.x << 7) + loff);
        float2 v3 = *(const float2*)(x + ((size_t)m3.x << 7) + loff);
        ax = fmaf(__int_as_float(m0.y), v0.x, ax);
        ay = fmaf(__int_as_float(m0.y), v0.y, ay);
        ax = fmaf(__int_as_float(m1.y), v1.x, ax);
        ay = fmaf(__int_as_float(m1.y), v1.y, ay);
        ax = fmaf(__int_as_float(m2.y), v2.x, ax);
        ay = fmaf(__int_as_float(m2.y), v2.y, ay);
        ax = fmaf(__int_as_float(m3.y), v3.x, ax);
        ay = fmaf(__int_as_float(m3.y), v3.y, ay);
    }
    for (; j < end; ++j) {
        int2 m = meta[j];
        float2 v = *(const float2*)(x + ((size_t)m.x << 7) + loff);
        ax = fmaf(__int_as_float(m.y), v.x, ax);
        ay = fmaf(__int_as_float(m.y), v.y, ay);
    }

    const size_t o = ((size_t)node << 7) + loff;
    if (store_next) *(float2*)(nxt + o) = make_float2(ax, ay);
    float2 f = *(float2*)(feat + o);
    f.x = fmaf(w, ax, f.x);
    f.y = fmaf(w, ay, f.y);
    *(float2*)(feat + o) = f;
}

// ---------------- output GEMM: out = [feat_s | feat_t] @ Wn + bn ------------
// 256 threads, 64 rows x 64 cols per block, BK=64, 16 acc/thread.
__global__ __launch_bounds__(256) void gemm_out(
    const float* __restrict__ fs,     // [N, HID]
    const float* __restrict__ ft,     // [N, HID]
    const float* __restrict__ Wn,     // [2*HID, OUT]
    const float* __restrict__ bn,     // [OUT]
    float* __restrict__ out)          // [N, OUT]
{
    __shared__ __align__(16) float at[64][76];   // A transposed [kk][row]
    __shared__ __align__(16) float bs[64][OUT];  // Wn chunk [kk][j]
    const int tid = threadIdx.x;
    const int tx = tid & 15;          // cols tx*4 .. tx*4+3
    const int ty = tid >> 4;          // rows ty*4 .. ty*4+3
    const int row0 = blockIdx.x * 64;

    float acc[4][4];
#pragma unroll
    for (int r = 0; r < 4; ++r)
#pragma unroll
        for (int c = 0; c < 4; ++c) acc[r][c] = 0.f;

    for (int chunk = 0; chunk < 4; ++chunk) {
        const float* Xsrc = (chunk < 2) ? fs : ft;
        const int kbase = (chunk & 1) * 64;
        // stage A transposed: 64 rows x 64 k
        {
            int lc = tid & 15, lr = tid >> 4;
#pragma unroll
            for (int p = 0; p < 4; ++p) {
                int r = lr + p * 16;
                int grow = row0 + r; if (grow > N_NODES - 1) grow = N_NODES - 1;
                float4 v = *(const float4*)(Xsrc + (size_t)grow * HID + kbase + lc * 4);
                float vv[4] = {v.x, v.y, v.z, v.w};
#pragma unroll
                for (int i = 0; i < 4; ++i) {
                    int ii = (i + lc) & 3;
                    at[lc * 4 + ii][r] = vv[ii];
                }
            }
        }
        // stage B
        {
            int jf = tid & 15, kk0 = tid >> 4;
#pragma unroll
            for (int p = 0; p < 4; ++p) {
                int kk = kk0 + p * 16;
                *(float4*)&bs[kk][jf * 4] =
                    *(const float4*)(Wn + (size_t)(chunk * 64 + kk) * OUT + jf * 4);
            }
        }
        __syncthreads();
#pragma unroll 8
        for (int kk = 0; kk < 64; ++kk) {
            float4 a = *(const float4*)&at[kk][ty * 4];
            float4 b = *(const float4*)&bs[kk][tx * 4];
            float av[4] = {a.x, a.y, a.z, a.w};
            float bv[4] = {b.x, b.y, b.z, b.w};
#pragma unroll
            for (int r = 0; r < 4; ++r)
#pragma unroll
                for (int c = 0; c < 4; ++c)
                    acc[r][c] = fmaf(av[r], bv[c], acc[r][c]);
        }
        __syncthreads();
    }

    float4 bj = *(const float4*)(bn + tx * 4);
    float bjv[4] = {bj.x, bj.y, bj.z, bj.w};
#pragma unroll
    for (int r = 0; r < 4; ++r) {
        int grow = row0 + ty * 4 + r;
        if (grow < N_NODES) {
            size_t off = (size_t)grow * OUT + tx * 4;
            *(float4*)(out + off) = make_float4(acc[r][0] + bjv[0], acc[r][1] + bjv[1],
                                                acc[r][2] + bjv[2], acc[r][3] + bjv[3]);
        }
    }
}

extern "C" void kernel_launch(void* const* d_in, const int* in_sizes, int n_in,
                              void* d_out, int out_size, void* d_ws, size_t ws_size,
                              hipStream_t stream) {
    const float* fsrc = (const float*)d_in[0];
    const float* ftgt = (const float*)d_in[1];
    const int*   erow = (const int*)d_in[2];
    const int*   ecol = (const int*)d_in[3];
    const float* ew   = (const float*)d_in[4];
    const float* Wsrc = (const float*)d_in[5];
    const float* bsrc = (const float*)d_in[6];
    const float* Wtgt = (const float*)d_in[7];
    const float* btgt = (const float*)d_in[8];
    const float* ws   = (const float*)d_in[9];
    const float* wt   = (const float*)d_in[10];
    const float* Wn   = (const float*)d_in[11];
    const float* bn   = (const float*)d_in[12];
    float* out = (float*)d_out;

    const size_t buf = (size_t)N_NODES * HID;
    char* p = (char*)d_ws;
    float* curr_s = (float*)p; p += buf * 4;
    float* curr_t = (float*)p; p += buf * 4;
    float* next_s = (float*)p; p += buf * 4;
    float* next_t = (float*)p; p += buf * 4;
    float* feat_s = (float*)p; p += buf * 4;
    float* feat_t = (float*)p; p += buf * 4;
    int2* meta    = (int2*)p;  p += (size_t)2 * N_EDGES * 8;
    int* rowptr   = (int*)p;   p += (size_t)(NTOT + 4) * 4;
    int* cnt      = (int*)p;   p += (size_t)NTOT * 4;
    int* local    = (int*)p;   p += (size_t)NTOT * 4;
    int* cursor   = (int*)p;   p += (size_t)NTOT * 4;
    int* chunksum = (int*)p;   p += 256 * 4;
    int* chunkoff = (int*)p;   p += 256 * 4;

    const int eb = (N_EDGES + 255) / 256;

    // input GEMMs (independent of CSR build)
    const int gblocks = (N_NODES + 63) / 64;
    gemm_in<<<gblocks, 256, 0, stream>>>(fsrc, Wsrc, bsrc, ws, curr_s, feat_s);
    gemm_in<<<gblocks, 256, 0, stream>>>(ftgt, Wtgt, btgt, wt, curr_t, feat_t);

    // combined CSR build (both directions share one scan; t-rows at NPAD offset)
    hipMemsetAsync(cnt, 0, (size_t)NTOT * 4, stream);
    hipMemsetAsync(cursor, 0, (size_t)NTOT * 4, stream);
    hist2_k<<<eb, 256, 0, stream>>>(erow, ecol, cnt);
    scan1_k<<<NCHUNK2, 256, 0, stream>>>(cnt, local, chunksum);
    scan2_k<<<1, 256, 0, stream>>>(chunksum, chunkoff, rowptr);
    scan3_k<<<NCHUNK2, 256, 0, stream>>>(local, chunkoff, rowptr);
    fill2_k<<<eb, 256, 0, stream>>>(erow, ecol, ew, rowptr, cursor, meta);

    // 3 hops, both directions per launch, axpy fused
    const int sblocks = NTOT / 4;
    for (int h = 1; h <= HOPS; ++h) {
        spmm_k<<<sblocks, 256, 0, stream>>>(rowptr, meta,
                                            curr_s, curr_t, next_s, next_t,
                                            feat_s, feat_t, ws, wt,
                                            h, (h < HOPS) ? 1 : 0);
        float* t;
        t = curr_s; curr_s = next_s; next_s = t;
        t = curr_t; curr_t = next_t; next_t = t;
    }

    gemm_out<<<gblocks, 256, 0, stream>>>(feat_s, feat_t, Wn, bn, out);
}

// Round 4
// 1542.198 us; speedup vs baseline: 10.5878x; 1.4219x over previous
//
#include <hip/hip_runtime.h>

#define N_NODES 100000
#define N_EDGES 3200000
#define FEAT 256
#define HID 128
#define OUT 64
#define HOPS 3

#define CHUNK 1024                                   // elements scanned per block
#define NCHUNK ((N_NODES + CHUNK - 1) / CHUNK)       // 98
#define NPAD (NCHUNK * CHUNK)                        // 100352
#define NTOT (2 * NPAD)                              // combined s|t node space
#define NCHUNK2 (NTOT / CHUNK)                       // 196

typedef unsigned short ushort_t;

__device__ __forceinline__ float bf2f(ushort_t u) {
    return __uint_as_float(((unsigned)u) << 16);
}
// pack two f32 -> two bf16 (round-to-nearest-even) in one uint
__device__ __forceinline__ unsigned pack_bf16(float a, float b) {
    unsigned ua = __float_as_uint(a);
    unsigned ub = __float_as_uint(b);
    ua += 0x7fffu + ((ua >> 16) & 1u);
    ub += 0x7fffu + ((ub >> 16) & 1u);
    return (ua >> 16) | (ub & 0xffff0000u);
}

// ---------------- CSR build: histogram (both directions, one pass) ---------
__global__ __launch_bounds__(256) void hist2_k(
    const int* __restrict__ erow, const int* __restrict__ ecol,
    int* __restrict__ cnt)
{
    int e = blockIdx.x * 256 + threadIdx.x;
    if (e < N_EDGES) {
        atomicAdd(&cnt[erow[e]], 1);          // s: dst = row
        atomicAdd(&cnt[NPAD + ecol[e]], 1);   // t: dst = col
    }
}

// ---------------- hierarchical exclusive scan over NTOT --------------------
__global__ __launch_bounds__(256) void scan1_k(
    const int* __restrict__ cnt, int* __restrict__ local, int* __restrict__ chunksum)
{
    __shared__ int sdata[256];
    const int tid = threadIdx.x;
    const int base = blockIdx.x * CHUNK;

    int4 v = ((const int4*)(cnt + base))[tid];
    int tsum = v.x + v.y + v.z + v.w;
    sdata[tid] = tsum;
    __syncthreads();
    for (int off = 1; off < 256; off <<= 1) {
        int t = (tid >= off) ? sdata[tid - off] : 0;
        __syncthreads();
        sdata[tid] += t;
        __syncthreads();
    }
    int excl = sdata[tid] - tsum;
    int4 o;
    o.x = excl;
    o.y = excl + v.x;
    o.z = o.y + v.y;
    o.w = o.z + v.z;
    ((int4*)(local + base))[tid] = o;
    if (tid == 255) chunksum[blockIdx.x] = sdata[255];
}

__global__ __launch_bounds__(256) void scan2_k(
    const int* __restrict__ chunksum, int* __restrict__ chunkoff, int* __restrict__ rowptr)
{
    __shared__ int sdata[256];
    const int tid = threadIdx.x;
    int v = (tid < NCHUNK2) ? chunksum[tid] : 0;
    sdata[tid] = v;
    __syncthreads();
    for (int off = 1; off < 256; off <<= 1) {
        int t = (tid >= off) ? sdata[tid - off] : 0;
        __syncthreads();
        sdata[tid] += t;
        __syncthreads();
    }
    int excl = sdata[tid] - v;
    if (tid < NCHUNK2) chunkoff[tid] = excl;
    if (tid == NCHUNK2 - 1) rowptr[NTOT] = excl + v;   // == 2*N_EDGES
}

__global__ __launch_bounds__(256) void scan3_k(
    const int* __restrict__ local, const int* __restrict__ chunkoff,
    int* __restrict__ rowptr)
{
    const int off = chunkoff[blockIdx.x];
    const int i = blockIdx.x * CHUNK + threadIdx.x * 4;
    int4 v = *(const int4*)(local + i);
    v.x += off; v.y += off; v.z += off; v.w += off;
    *(int4*)(rowptr + i) = v;
}

// ---------------- fill both CSRs in one pass -------------------------------
__global__ __launch_bounds__(256) void fill2_k(
    const int* __restrict__ erow, const int* __restrict__ ecol,
    const float* __restrict__ ew,
    const int* __restrict__ rowptr, int* __restrict__ cursor,
    int2* __restrict__ meta)
{
    int e = blockIdx.x * 256 + threadIdx.x;
    if (e >= N_EDGES) return;
    int r = erow[e], c = ecol[e];
    int wbits = __float_as_int(ew[e]);
    int ps = rowptr[r] + atomicAdd(&cursor[r], 1);
    meta[ps] = make_int2(c, wbits);                         // s: src = col
    int pt = rowptr[NPAD + c] + atomicAdd(&cursor[NPAD + c], 1);
    meta[pt] = make_int2(r, wbits);                         // t: src = row
}

// ---------------- input GEMM: h0 = bf16(X @ W + b) --------------------------
// 256 threads, 64 rows x 128 cols per block, BK=32, 32 acc/thread.
__global__ __launch_bounds__(256) void gemm_in(
    const float* __restrict__ X,      // [N, FEAT]
    const float* __restrict__ W,      // [FEAT, HID]
    const float* __restrict__ bias,   // [HID]
    ushort_t* __restrict__ h0)        // [N, HID] bf16
{
    __shared__ __align__(16) float at[32][76];   // A transposed [kk][row]
    __shared__ __align__(16) float bs[32][HID];  // W chunk [kk][j]
    const int tid = threadIdx.x;
    const int tx = tid & 31;          // col group: cols tx*4 .. tx*4+3
    const int ty = tid >> 5;          // row group: rows ty*8 .. ty*8+7
    const int row0 = blockIdx.x * 64;

    float acc[8][4];
#pragma unroll
    for (int r = 0; r < 8; ++r)
#pragma unroll
        for (int c = 0; c < 4; ++c) acc[r][c] = 0.f;

    const int lc = tid & 7;           // f4 index within 32-wide K chunk
    const int lr = tid >> 3;          // 0..31

    for (int k0 = 0; k0 < FEAT; k0 += 32) {
        // stage A transposed
#pragma unroll
        for (int p = 0; p < 2; ++p) {
            int r = lr + p * 32;
            int grow = row0 + r; if (grow > N_NODES - 1) grow = N_NODES - 1;
            float4 v = *(const float4*)(X + (size_t)grow * FEAT + k0 + lc * 4);
            float vv[4] = {v.x, v.y, v.z, v.w};
#pragma unroll
            for (int i = 0; i < 4; ++i) {
                int ii = (i + lc) & 3;           // rotate to spread banks
                at[lc * 4 + ii][r] = vv[ii];
            }
        }
        // stage B
        {
            int jf = tid & 31, kk0 = tid >> 5;
#pragma unroll
            for (int p = 0; p < 4; ++p) {
                int kk = kk0 + p * 8;
                *(float4*)&bs[kk][jf * 4] =
                    *(const float4*)(W + (size_t)(k0 + kk) * HID + jf * 4);
            }
        }
        __syncthreads();
#pragma unroll 4
        for (int kk = 0; kk < 32; ++kk) {
            float4 a0 = *(const float4*)&at[kk][ty * 8];
            float4 a1 = *(const float4*)&at[kk][ty * 8 + 4];
            float4 b  = *(const float4*)&bs[kk][tx * 4];
            float av[8] = {a0.x, a0.y, a0.z, a0.w, a1.x, a1.y, a1.z, a1.w};
            float bv[4] = {b.x, b.y, b.z, b.w};
#pragma unroll
            for (int r = 0; r < 8; ++r)
#pragma unroll
                for (int c = 0; c < 4; ++c)
                    acc[r][c] = fmaf(av[r], bv[c], acc[r][c]);
        }
        __syncthreads();
    }

    float4 bj = *(const float4*)(bias + tx * 4);
    float bjv[4] = {bj.x, bj.y, bj.z, bj.w};
#pragma unroll
    for (int r = 0; r < 8; ++r) {
        int grow = row0 + ty * 8 + r;
        if (grow < N_NODES) {
            float o[4];
#pragma unroll
            for (int c = 0; c < 4; ++c) o[c] = acc[r][c] + bjv[c];
            size_t off = (size_t)grow * HID + tx * 4;   // in ushorts
            uint2 pk = make_uint2(pack_bf16(o[0], o[1]), pack_bf16(o[2], o[3]));
            *(uint2*)(h0 + off) = pk;
        }
    }
}

// ---------------- pure SPMM, wave-per-row, both directions, bf16 -----------
// unit < NPAD: s-direction row=unit ; unit >= NPAD: t-direction row=unit-NPAD
__global__ __launch_bounds__(256) void spmm_k(
    const int* __restrict__ rowptr,
    const int2* __restrict__ meta,
    const ushort_t* __restrict__ xs, const ushort_t* __restrict__ xt,
    ushort_t* __restrict__ ns, ushort_t* __restrict__ nt)
{
    const int unit = blockIdx.x * 4 + (threadIdx.x >> 6);   // one wave per unit
    const int lane = threadIdx.x & 63;

    const ushort_t* x; ushort_t* nxt;
    int node;
    if (unit < NPAD) {
        node = unit;
        if (node >= N_NODES) return;
        x = xs; nxt = ns;
    } else {
        node = unit - NPAD;
        if (node >= N_NODES) return;
        x = xt; nxt = nt;
    }

    const int start = rowptr[unit];
    const int end   = rowptr[unit + 1];
    const int loff  = lane << 1;      // 2 bf16 cols per lane

    float ax = 0.f, ay = 0.f;
    int j = start;
    for (; j + 3 < end; j += 4) {
        int2 m0 = meta[j + 0];
        int2 m1 = meta[j + 1];
        int2 m2 = meta[j + 2];
        int2 m3 = meta[j + 3];
        unsigned u0 = *(const unsigned*)(x + ((size_t)m0.x << 7) + loff);
        unsigned u1 = *(const unsigned*)(x + ((size_t)m1.x << 7) + loff);
        unsigned u2 = *(const unsigned*)(x + ((size_t)m2.x << 7) + loff);
        unsigned u3 = *(const unsigned*)(x + ((size_t)m3.x << 7) + loff);
        float w0 = __int_as_float(m0.y), w1 = __int_as_float(m1.y);
        float w2 = __int_as_float(m2.y), w3 = __int_as_float(m3.y);
        ax = fmaf(w0, __uint_as_float(u0 << 16), ax);
        ay = fmaf(w0, __uint_as_float(u0 & 0xffff0000u), ay);
        ax = fmaf(w1, __uint_as_float(u1 << 16), ax);
        ay = fmaf(w1, __uint_as_float(u1 & 0xffff0000u), ay);
        ax = fmaf(w2, __uint_as_float(u2 << 16), ax);
        ay = fmaf(w2, __uint_as_float(u2 & 0xffff0000u), ay);
        ax = fmaf(w3, __uint_as_float(u3 << 16), ax);
        ay = fmaf(w3, __uint_as_float(u3 & 0xffff0000u), ay);
    }
    for (; j < end; ++j) {
        int2 m = meta[j];
        unsigned u = *(const unsigned*)(x + ((size_t)m.x << 7) + loff);
        float w = __int_as_float(m.y);
        ax = fmaf(w, __uint_as_float(u << 16), ax);
        ay = fmaf(w, __uint_as_float(u & 0xffff0000u), ay);
    }

    *(unsigned*)(nxt + ((size_t)node << 7) + loff) = pack_bf16(ax, ay);
}

// ---------------- output GEMM: out = [Σ ws_h·hs_h | Σ wt_h·ht_h] @ Wn + bn --
// 256 threads, 64 rows x 64 cols per block, BK=64, 16 acc/thread.
__global__ __launch_bounds__(256) void gemm_out(
    const ushort_t* __restrict__ s0, const ushort_t* __restrict__ s1,
    const ushort_t* __restrict__ s2, const ushort_t* __restrict__ s3,
    const ushort_t* __restrict__ t0, const ushort_t* __restrict__ t1,
    const ushort_t* __restrict__ t2, const ushort_t* __restrict__ t3,
    const float* __restrict__ wsv, const float* __restrict__ wtv,
    const float* __restrict__ Wn,     // [2*HID, OUT]
    const float* __restrict__ bn,     // [OUT]
    float* __restrict__ out)          // [N, OUT]
{
    __shared__ __align__(16) float at[64][76];   // A transposed [kk][row]
    __shared__ __align__(16) float bs[64][OUT];  // Wn chunk [kk][j]
    const int tid = threadIdx.x;
    const int tx = tid & 15;          // cols tx*4 .. tx*4+3
    const int ty = tid >> 4;          // rows ty*4 .. ty*4+3
    const int row0 = blockIdx.x * 64;

    const ushort_t* bufs[2][4] = {{s0, s1, s2, s3}, {t0, t1, t2, t3}};
    float wv[2][4];
#pragma unroll
    for (int h = 0; h < 4; ++h) { wv[0][h] = wsv[h]; wv[1][h] = wtv[h]; }

    float acc[4][4];
#pragma unroll
    for (int r = 0; r < 4; ++r)
#pragma unroll
        for (int c = 0; c < 4; ++c) acc[r][c] = 0.f;

#pragma unroll
    for (int chunk = 0; chunk < 4; ++chunk) {
        const int dir = chunk >> 1;
        const int kbase = (chunk & 1) * 64;
        // stage A transposed: 64 rows x 64 k of the weighted hop-sum
        {
            int lc = tid & 15, lr = tid >> 4;
#pragma unroll
            for (int p = 0; p < 4; ++p) {
                int r = lr + p * 16;
                int grow = row0 + r; if (grow > N_NODES - 1) grow = N_NODES - 1;
                size_t off = (size_t)grow * HID + kbase + lc * 4;
                float v[4] = {0.f, 0.f, 0.f, 0.f};
#pragma unroll
                for (int h = 0; h < 4; ++h) {
                    ushort4 u = *(const ushort4*)(bufs[dir][h] + off);
                    float w = wv[dir][h];
                    v[0] = fmaf(w, bf2f(u.x), v[0]);
                    v[1] = fmaf(w, bf2f(u.y), v[1]);
                    v[2] = fmaf(w, bf2f(u.z), v[2]);
                    v[3] = fmaf(w, bf2f(u.w), v[3]);
                }
#pragma unroll
                for (int i = 0; i < 4; ++i) {
                    int ii = (i + lc) & 3;
                    at[lc * 4 + ii][r] = v[ii];
                }
            }
        }
        // stage B
        {
            int jf = tid & 15, kk0 = tid >> 4;
#pragma unroll
            for (int p = 0; p < 4; ++p) {
                int kk = kk0 + p * 16;
                *(float4*)&bs[kk][jf * 4] =
                    *(const float4*)(Wn + (size_t)(chunk * 64 + kk) * OUT + jf * 4);
            }
        }
        __syncthreads();
#pragma unroll 8
        for (int kk = 0; kk < 64; ++kk) {
            float4 a = *(const float4*)&at[kk][ty * 4];
            float4 b = *(const float4*)&bs[kk][tx * 4];
            float av[4] = {a.x, a.y, a.z, a.w};
            float bv[4] = {b.x, b.y, b.z, b.w};
#pragma unroll
            for (int r = 0; r < 4; ++r)
#pragma unroll
                for (int c = 0; c < 4; ++c)
                    acc[r][c] = fmaf(av[r], bv[c], acc[r][c]);
        }
        __syncthreads();
    }

    float4 bj = *(const float4*)(bn + tx * 4);
    float bjv[4] = {bj.x, bj.y, bj.z, bj.w};
#pragma unroll
    for (int r = 0; r < 4; ++r) {
        int grow = row0 + ty * 4 + r;
        if (grow < N_NODES) {
            size_t off = (size_t)grow * OUT + tx * 4;
            *(float4*)(out + off) = make_float4(acc[r][0] + bjv[0], acc[r][1] + bjv[1],
                                                acc[r][2] + bjv[2], acc[r][3] + bjv[3]);
        }
    }
}

extern "C" void kernel_launch(void* const* d_in, const int* in_sizes, int n_in,
                              void* d_out, int out_size, void* d_ws, size_t ws_size,
                              hipStream_t stream) {
    const float* fsrc = (const float*)d_in[0];
    const float* ftgt = (const float*)d_in[1];
    const int*   erow = (const int*)d_in[2];
    const int*   ecol = (const int*)d_in[3];
    const float* ew   = (const float*)d_in[4];
    const float* Wsrc = (const float*)d_in[5];
    const float* bsrc = (const float*)d_in[6];
    const float* Wtgt = (const float*)d_in[7];
    const float* btgt = (const float*)d_in[8];
    const float* ws   = (const float*)d_in[9];
    const float* wt   = (const float*)d_in[10];
    const float* Wn   = (const float*)d_in[11];
    const float* bn   = (const float*)d_in[12];
    float* out = (float*)d_out;

    const size_t buf = (size_t)N_NODES * HID;   // elements per hop buffer
    char* p = (char*)d_ws;
    ushort_t* hs[4]; ushort_t* ht[4];
    for (int h = 0; h < 4; ++h) {
        hs[h] = (ushort_t*)p; p += buf * 2;
        ht[h] = (ushort_t*)p; p += buf * 2;
    }
    int2* meta    = (int2*)p;  p += (size_t)2 * N_EDGES * 8;
    int* rowptr   = (int*)p;   p += (size_t)(NTOT + 4) * 4;
    int* cnt      = (int*)p;   p += (size_t)NTOT * 4;
    int* local    = (int*)p;   p += (size_t)NTOT * 4;
    int* cursor   = (int*)p;   p += (size_t)NTOT * 4;
    int* chunksum = (int*)p;   p += 256 * 4;
    int* chunkoff = (int*)p;   p += 256 * 4;

    const int eb = (N_EDGES + 255) / 256;

    // input GEMMs -> bf16 hop-0 buffers
    const int gblocks = (N_NODES + 63) / 64;
    gemm_in<<<gblocks, 256, 0, stream>>>(fsrc, Wsrc, bsrc, hs[0]);
    gemm_in<<<gblocks, 256, 0, stream>>>(ftgt, Wtgt, btgt, ht[0]);

    // combined CSR build (both directions share one scan; t-rows at NPAD offset)
    hipMemsetAsync(cnt, 0, (size_t)NTOT * 4, stream);
    hipMemsetAsync(cursor, 0, (size_t)NTOT * 4, stream);
    hist2_k<<<eb, 256, 0, stream>>>(erow, ecol, cnt);
    scan1_k<<<NCHUNK2, 256, 0, stream>>>(cnt, local, chunksum);
    scan2_k<<<1, 256, 0, stream>>>(chunksum, chunkoff, rowptr);
    scan3_k<<<NCHUNK2, 256, 0, stream>>>(local, chunkoff, rowptr);
    fill2_k<<<eb, 256, 0, stream>>>(erow, ecol, ew, rowptr, cursor, meta);

    // 3 hops, both directions per launch, pure SPMM (weighted sum deferred)
    const int sblocks = NTOT / 4;
    for (int h = 1; h <= HOPS; ++h) {
        spmm_k<<<sblocks, 256, 0, stream>>>(rowptr, meta,
                                            hs[h - 1], ht[h - 1], hs[h], ht[h]);
    }

    gemm_out<<<gblocks, 256, 0, stream>>>(hs[0], hs[1], hs[2], hs[3],
                                          ht[0], ht[1], ht[2], ht[3],
                                          ws, wt, Wn, bn, out);
}

// Round 5
// 996.017 us; speedup vs baseline: 16.3938x; 1.5484x over previous
//
#include <hip/hip_runtime.h>

#define N_NODES 100000
#define N_EDGES 3200000
#define FEAT 256
#define HID 128
#define OUT 64
#define HOPS 3

#define NPAD 100352                      // 98*1024, >= N_NODES
#define NTOT (2 * NPAD)                  // combined s|t dst-unit space = 200704
#define NBUCK 196                        // NTOT / 1024 buckets (1024 units each)
#define EPB 2048                         // edges per block in CSR-build passes

typedef unsigned short ushort_t;

__device__ __forceinline__ float bf2f(ushort_t u) {
    return __uint_as_float(((unsigned)u) << 16);
}
__device__ __forceinline__ ushort_t f2bf(float a) {
    unsigned ua = __float_as_uint(a);
    ua += 0x7fffu + ((ua >> 16) & 1u);
    return (ushort_t)(ua >> 16);
}
__device__ __forceinline__ unsigned pack_bf16(float a, float b) {
    unsigned ua = __float_as_uint(a);
    unsigned ub = __float_as_uint(b);
    ua += 0x7fffu + ((ua >> 16) & 1u);
    ub += 0x7fffu + ((ub >> 16) & 1u);
    return (ua >> 16) | (ub & 0xffff0000u);
}

// ---------------- weight fold: Wc = W_{src,tgt} @ Wn_half ; bc = b @ Wn_half
// blocks 0..255: Wc_s rows; 256..511: Wc_t rows; 512/513: bc_s/bc_t
__global__ __launch_bounds__(64) void wcomb_k(
    const float* __restrict__ Wsrc, const float* __restrict__ Wtgt,
    const float* __restrict__ bsrc, const float* __restrict__ btgt,
    const float* __restrict__ Wn,     // [2*HID, OUT]
    float* __restrict__ Wc,           // [512, 64]
    float* __restrict__ bc)           // [128]
{
    const int blk = blockIdx.x;
    const int j = threadIdx.x;
    if (blk < 512) {
        const float* Wsel = (blk < 256) ? Wsrc : Wtgt;
        const int i = blk & 255;
        const int koff = (blk < 256) ? 0 : HID;
        float acc = 0.f;
        for (int k = 0; k < HID; ++k)
            acc = fmaf(Wsel[i * HID + k], Wn[(koff + k) * OUT + j], acc);
        Wc[blk * OUT + j] = acc;
    } else {
        const float* bsel = (blk == 512) ? bsrc : btgt;
        const int koff = (blk == 512) ? 0 : HID;
        float acc = 0.f;
        for (int k = 0; k < HID; ++k)
            acc = fmaf(bsel[k], Wn[(koff + k) * OUT + j], acc);
        bc[(blk - 512) * OUT + j] = acc;
    }
}

// ---------------- input GEMM: h0 = bf16(X @ Wc + bc) ------------------------
// 256 threads, 64 rows x 64 cols per block, K=256 in 4 chunks of 64.
__global__ __launch_bounds__(256) void gemm_in(
    const float* __restrict__ X,      // [N, FEAT]
    const float* __restrict__ B,      // [FEAT, OUT] folded weights
    const float* __restrict__ bias,   // [OUT] folded bias
    ushort_t* __restrict__ h0)        // [N, OUT] bf16
{
    __shared__ __align__(16) float at[64][76];   // A transposed [kk][row]
    __shared__ __align__(16) float bs[64][OUT];  // B chunk [kk][j]
    const int tid = threadIdx.x;
    const int tx = tid & 15;          // cols tx*4 .. tx*4+3
    const int ty = tid >> 4;          // rows ty*4 .. ty*4+3
    const int row0 = blockIdx.x * 64;

    float acc[4][4];
#pragma unroll
    for (int r = 0; r < 4; ++r)
#pragma unroll
        for (int c = 0; c < 4; ++c) acc[r][c] = 0.f;

    for (int chunk = 0; chunk < 4; ++chunk) {
        const int kbase = chunk * 64;
        // stage A transposed: 64 rows x 64 k
        {
            int lc = tid & 15, lr = tid >> 4;
#pragma unroll
            for (int p = 0; p < 4; ++p) {
                int r = lr + p * 16;
                int grow = row0 + r; if (grow > N_NODES - 1) grow = N_NODES - 1;
                float4 v = *(const float4*)(X + (size_t)grow * FEAT + kbase + lc * 4);
                float vv[4] = {v.x, v.y, v.z, v.w};
#pragma unroll
                for (int i = 0; i < 4; ++i) {
                    int ii = (i + lc) & 3;       // rotate to spread banks
                    at[lc * 4 + ii][r] = vv[ii];
                }
            }
        }
        // stage B
        {
            int jf = tid & 15, kk0 = tid >> 4;
#pragma unroll
            for (int p = 0; p < 4; ++p) {
                int kk = kk0 + p * 16;
                *(float4*)&bs[kk][jf * 4] =
                    *(const float4*)(B + (size_t)(kbase + kk) * OUT + jf * 4);
            }
        }
        __syncthreads();
#pragma unroll 8
        for (int kk = 0; kk < 64; ++kk) {
            float4 a = *(const float4*)&at[kk][ty * 4];
            float4 b = *(const float4*)&bs[kk][tx * 4];
            float av[4] = {a.x, a.y, a.z, a.w};
            float bv[4] = {b.x, b.y, b.z, b.w};
#pragma unroll
            for (int r = 0; r < 4; ++r)
#pragma unroll
                for (int c = 0; c < 4; ++c)
                    acc[r][c] = fmaf(av[r], bv[c], acc[r][c]);
        }
        __syncthreads();
    }

    float4 bj = *(const float4*)(bias + tx * 4);
    float bjv[4] = {bj.x, bj.y, bj.z, bj.w};
#pragma unroll
    for (int r = 0; r < 4; ++r) {
        int grow = row0 + ty * 4 + r;
        if (grow < N_NODES) {
            float o[4];
#pragma unroll
            for (int c = 0; c < 4; ++c) o[c] = acc[r][c] + bjv[c];
            size_t off = (size_t)grow * OUT + tx * 4;   // in ushorts
            *(uint2*)(h0 + off) = make_uint2(pack_bf16(o[0], o[1]), pack_bf16(o[2], o[3]));
        }
    }
}

// ---------------- CSR build pass 1a: bucket counts (LDS-reduced) -----------
__global__ __launch_bounds__(256) void p1a_cnt(
    const int* __restrict__ erow, const int* __restrict__ ecol,
    int* __restrict__ bucketcnt)
{
    __shared__ int h[256];
    const int tid = threadIdx.x;
    h[tid] = 0;
    __syncthreads();
    const int base = blockIdx.x * EPB;
    const int n = min(EPB, N_EDGES - base);
#pragma unroll
    for (int k = 0; k < 8; ++k) {
        int i = k * 256 + tid;
        if (i < n) {
            int e = base + i;
            atomicAdd(&h[erow[e] >> 10], 1);
            atomicAdd(&h[(NPAD + ecol[e]) >> 10], 1);
        }
    }
    __syncthreads();
    if (h[tid] > 0) atomicAdd(&bucketcnt[tid], h[tid]);
}

// ---------------- CSR build pass 1b: scan bucket counts -> bases -----------
__global__ __launch_bounds__(256) void p1a_scan(
    const int* __restrict__ bucketcnt,
    int* __restrict__ bbase, int* __restrict__ bcur, int* __restrict__ rowptr)
{
    __shared__ int sdata[256];
    const int tid = threadIdx.x;
    int v = (tid < NBUCK) ? bucketcnt[tid] : 0;
    sdata[tid] = v;
    __syncthreads();
    for (int off = 1; off < 256; off <<= 1) {
        int t = (tid >= off) ? sdata[tid - off] : 0;
        __syncthreads();
        sdata[tid] += t;
        __syncthreads();
    }
    int excl = sdata[tid] - v;
    bbase[tid] = (tid < NBUCK) ? excl : 2 * N_EDGES;
    bcur[tid] = excl;
    if (tid == 0) {
        bbase[NBUCK] = 2 * N_EDGES;
        rowptr[NTOT] = 2 * N_EDGES;
    }
}

// ---------------- CSR build pass 2: multisplit scatter into buckets --------
// entry: .x = src(17b) | dstlow(10b)<<17 ; .y = weight bits
__global__ __launch_bounds__(256) void fill_p1(
    const int* __restrict__ erow, const int* __restrict__ ecol,
    const float* __restrict__ ew,
    int* __restrict__ bcur, int2* __restrict__ meta_tmp)
{
    __shared__ int2 stage[2 * EPB];
    __shared__ unsigned char bkt[2 * EPB];
    __shared__ int lcnt[256], loff[256], gbase[256], cur[256];
    __shared__ int sdata[256];
    const int tid = threadIdx.x;
    const int base = blockIdx.x * EPB;
    const int n = min(EPB, N_EDGES - base);

    int r[8], c[8], wb[8];
    lcnt[tid] = 0;
    __syncthreads();
#pragma unroll
    for (int k = 0; k < 8; ++k) {
        int i = k * 256 + tid;
        if (i < n) {
            int e = base + i;
            r[k] = erow[e];
            c[k] = ecol[e];
            wb[k] = __float_as_int(ew[e]);
            atomicAdd(&lcnt[r[k] >> 10], 1);
            atomicAdd(&lcnt[(NPAD + c[k]) >> 10], 1);
        } else {
            r[k] = -1;
        }
    }
    __syncthreads();
    // exclusive scan of lcnt
    sdata[tid] = lcnt[tid];
    __syncthreads();
    for (int off = 1; off < 256; off <<= 1) {
        int t = (tid >= off) ? sdata[tid - off] : 0;
        __syncthreads();
        sdata[tid] += t;
        __syncthreads();
    }
    loff[tid] = sdata[tid] - lcnt[tid];
    cur[tid] = loff[tid];
    // reserve global space per bucket
    gbase[tid] = (lcnt[tid] > 0) ? atomicAdd(&bcur[tid], lcnt[tid]) : 0;
    __syncthreads();
    // scatter into LDS stage grouped by bucket
#pragma unroll
    for (int k = 0; k < 8; ++k) {
        if (r[k] >= 0) {
            int bs_ = r[k] >> 10;
            int l = atomicAdd(&cur[bs_], 1);
            stage[l] = make_int2(c[k] | ((r[k] & 1023) << 17), wb[k]);
            bkt[l] = (unsigned char)bs_;
            int ut = NPAD + c[k];
            int bt_ = ut >> 10;
            int l2 = atomicAdd(&cur[bt_], 1);
            stage[l2] = make_int2(r[k] | ((ut & 1023) << 17), wb[k]);
            bkt[l2] = (unsigned char)bt_;
        }
    }
    __syncthreads();
    // flush: per-bucket runs are contiguous -> coalesced global writes
    const int tot = 2 * n;
    for (int i = tid; i < tot; i += 256) {
        int b = bkt[i];
        meta_tmp[(size_t)gbase[b] + (i - loff[b])] = stage[i];
    }
}

// ---------------- CSR build pass 3: within-bucket sort + rowptr ------------
// one block per bucket (1024 dst-units, ~260KB segment, L2-resident)
__global__ __launch_bounds__(256) void fill_p2(
    const int* __restrict__ bbase,
    const int2* __restrict__ meta_tmp,
    int2* __restrict__ meta, int* __restrict__ rowptr)
{
    __shared__ int cnt[1024];
    __shared__ int sdata[256];
    const int tid = threadIdx.x;
    const int b = blockIdx.x;
    const int u0 = b << 10;
    const int seg0 = bbase[b];
    const int seg1 = bbase[b + 1];

    for (int i = tid; i < 1024; i += 256) cnt[i] = 0;
    __syncthreads();
    for (int j = seg0 + tid; j < seg1; j += 256) {
        int2 e = meta_tmp[j];
        atomicAdd(&cnt[(e.x >> 17) & 1023], 1);
    }
    __syncthreads();
    // exclusive scan over 1024 (int4 per thread)
    int4 v = *(int4*)&cnt[tid * 4];
    int tsum = v.x + v.y + v.z + v.w;
    sdata[tid] = tsum;
    __syncthreads();
    for (int off = 1; off < 256; off <<= 1) {
        int t = (tid >= off) ? sdata[tid - off] : 0;
        __syncthreads();
        sdata[tid] += t;
        __syncthreads();
    }
    int excl = sdata[tid] - tsum;
    int4 o;
    o.x = seg0 + excl;
    o.y = o.x + v.x;
    o.z = o.y + v.y;
    o.w = o.z + v.z;
    *(int4*)(rowptr + u0 + tid * 4) = o;   // rowptr written here (absolute)
    *(int4*)&cnt[tid * 4] = o;             // cursors (absolute)
    __syncthreads();
    for (int j = seg0 + tid; j < seg1; j += 256) {
        int2 e = meta_tmp[j];
        int pos = atomicAdd(&cnt[(e.x >> 17) & 1023], 1);
        meta[pos] = make_int2(e.x & 0x1ffff, e.y);
    }
}

// ---------------- pure SPMM, wave-per-row, both directions, bf16, 64 cols --
__global__ __launch_bounds__(256) void spmm_k(
    const int* __restrict__ rowptr,
    const int2* __restrict__ meta,
    const ushort_t* __restrict__ xs, const ushort_t* __restrict__ xt,
    ushort_t* __restrict__ ns, ushort_t* __restrict__ nt)
{
    const int unit = blockIdx.x * 4 + (threadIdx.x >> 6);   // one wave per unit
    const int lane = threadIdx.x & 63;

    const ushort_t* x; ushort_t* nxt;
    int node;
    if (unit < NPAD) {
        node = unit;
        if (node >= N_NODES) return;
        x = xs; nxt = ns;
    } else {
        node = unit - NPAD;
        if (node >= N_NODES) return;
        x = xt; nxt = nt;
    }

    const int start = rowptr[unit];
    const int end   = rowptr[unit + 1];

    float a = 0.f;
    int j = start;
    for (; j + 7 < end; j += 8) {
        int2 m0 = meta[j + 0], m1 = meta[j + 1], m2 = meta[j + 2], m3 = meta[j + 3];
        int2 m4 = meta[j + 4], m5 = meta[j + 5], m6 = meta[j + 6], m7 = meta[j + 7];
        float v0 = bf2f(x[((size_t)m0.x << 6) + lane]);
        float v1 = bf2f(x[((size_t)m1.x << 6) + lane]);
        float v2 = bf2f(x[((size_t)m2.x << 6) + lane]);
        float v3 = bf2f(x[((size_t)m3.x << 6) + lane]);
        float v4 = bf2f(x[((size_t)m4.x << 6) + lane]);
        float v5 = bf2f(x[((size_t)m5.x << 6) + lane]);
        float v6 = bf2f(x[((size_t)m6.x << 6) + lane]);
        float v7 = bf2f(x[((size_t)m7.x << 6) + lane]);
        a = fmaf(__int_as_float(m0.y), v0, a);
        a = fmaf(__int_as_float(m1.y), v1, a);
        a = fmaf(__int_as_float(m2.y), v2, a);
        a = fmaf(__int_as_float(m3.y), v3, a);
        a = fmaf(__int_as_float(m4.y), v4, a);
        a = fmaf(__int_as_float(m5.y), v5, a);
        a = fmaf(__int_as_float(m6.y), v6, a);
        a = fmaf(__int_as_float(m7.y), v7, a);
    }
    for (; j < end; ++j) {
        int2 m = meta[j];
        a = fmaf(__int_as_float(m.y), bf2f(x[((size_t)m.x << 6) + lane]), a);
    }

    nxt[((size_t)node << 6) + lane] = f2bf(a);
}

// ---------------- combine: out = Σ ws[h]·hs_h + Σ wt[h]·ht_h + bn ----------
__global__ __launch_bounds__(256) void combine_k(
    const ushort_t* __restrict__ s0, const ushort_t* __restrict__ s1,
    const ushort_t* __restrict__ s2, const ushort_t* __restrict__ s3,
    const ushort_t* __restrict__ t0, const ushort_t* __restrict__ t1,
    const ushort_t* __restrict__ t2, const ushort_t* __restrict__ t3,
    const float* __restrict__ wsv, const float* __restrict__ wtv,
    const float* __restrict__ bn,
    float* __restrict__ out)
{
    const int gid = blockIdx.x * 256 + threadIdx.x;   // one per 4 cols
    if (gid >= N_NODES * (OUT / 4)) return;
    const size_t off = (size_t)gid * 4;

    float4 b = ((const float4*)bn)[gid & (OUT / 4 - 1)];
    float acc[4] = {b.x, b.y, b.z, b.w};

    const ushort_t* bufs[8] = {s0, s1, s2, s3, t0, t1, t2, t3};
    float w[8];
#pragma unroll
    for (int h = 0; h < 4; ++h) { w[h] = wsv[h]; w[4 + h] = wtv[h]; }

#pragma unroll
    for (int h = 0; h < 8; ++h) {
        ushort4 u = *(const ushort4*)(bufs[h] + off);
        acc[0] = fmaf(w[h], bf2f(u.x), acc[0]);
        acc[1] = fmaf(w[h], bf2f(u.y), acc[1]);
        acc[2] = fmaf(w[h], bf2f(u.z), acc[2]);
        acc[3] = fmaf(w[h], bf2f(u.w), acc[3]);
    }
    *(float4*)(out + off) = make_float4(acc[0], acc[1], acc[2], acc[3]);
}

extern "C" void kernel_launch(void* const* d_in, const int* in_sizes, int n_in,
                              void* d_out, int out_size, void* d_ws, size_t ws_size,
                              hipStream_t stream) {
    const float* fsrc = (const float*)d_in[0];
    const float* ftgt = (const float*)d_in[1];
    const int*   erow = (const int*)d_in[2];
    const int*   ecol = (const int*)d_in[3];
    const float* ew   = (const float*)d_in[4];
    const float* Wsrc = (const float*)d_in[5];
    const float* bsrc = (const float*)d_in[6];
    const float* Wtgt = (const float*)d_in[7];
    const float* btgt = (const float*)d_in[8];
    const float* ws   = (const float*)d_in[9];
    const float* wt   = (const float*)d_in[10];
    const float* Wn   = (const float*)d_in[11];
    const float* bn   = (const float*)d_in[12];
    float* out = (float*)d_out;

    const size_t buf = (size_t)N_NODES * OUT;   // elements per hop buffer (64-dim)
    char* p = (char*)d_ws;
    ushort_t* hs[4]; ushort_t* ht[4];
    for (int h = 0; h < 4; ++h) {
        hs[h] = (ushort_t*)p; p += buf * 2;
        ht[h] = (ushort_t*)p; p += buf * 2;
    }
    int2* meta     = (int2*)p;  p += (size_t)2 * N_EDGES * 8;
    int2* meta_tmp = (int2*)p;  p += (size_t)2 * N_EDGES * 8;
    int* rowptr    = (int*)p;   p += (size_t)(NTOT + 16) * 4;
    float* Wc      = (float*)p; p += 512 * OUT * 4;
    float* bc      = (float*)p; p += 128 * 4;
    int* bbase     = (int*)p;   p += 260 * 4;
    int* bucketcnt = (int*)p;   p += 256 * 4;
    int* bcur      = (int*)p;   p += 256 * 4;

    const int eblocks = (N_EDGES + EPB - 1) / EPB;   // 1563
    const int gblocks = (N_NODES + 63) / 64;         // 1563

    // fold output projection into input weights
    wcomb_k<<<514, 64, 0, stream>>>(Wsrc, Wtgt, bsrc, btgt, Wn, Wc, bc);

    // input GEMMs -> bf16 hop-0 buffers (already projected to 64 dims)
    gemm_in<<<gblocks, 256, 0, stream>>>(fsrc, Wc, bc, hs[0]);
    gemm_in<<<gblocks, 256, 0, stream>>>(ftgt, Wc + 256 * OUT, bc + OUT, ht[0]);

    // CSR build: bucket counts -> bases -> multisplit -> within-bucket sort
    hipMemsetAsync(bucketcnt, 0, 256 * sizeof(int), stream);
    p1a_cnt<<<eblocks, 256, 0, stream>>>(erow, ecol, bucketcnt);
    p1a_scan<<<1, 256, 0, stream>>>(bucketcnt, bbase, bcur, rowptr);
    fill_p1<<<eblocks, 256, 0, stream>>>(erow, ecol, ew, bcur, meta_tmp);
    fill_p2<<<NBUCK, 256, 0, stream>>>(bbase, meta_tmp, meta, rowptr);

    // 3 hops, both directions per launch
    const int sblocks = NTOT / 4;
    for (int h = 1; h <= HOPS; ++h) {
        spmm_k<<<sblocks, 256, 0, stream>>>(rowptr, meta,
                                            hs[h - 1], ht[h - 1], hs[h], ht[h]);
    }

    // final weighted combine + bias
    combine_k<<<(N_NODES * (OUT / 4) + 255) / 256, 256, 0, stream>>>(
        hs[0], hs[1], hs[2], hs[3], ht[0], ht[1], ht[2], ht[3], ws, wt, bn, out);
}

// Round 7
// 717.534 us; speedup vs baseline: 22.7565x; 1.3881x over previous
//
#include <hip/hip_runtime.h>

#define N_NODES 100000
#define N_EDGES 3200000
#define FEAT 256
#define HID 128
#define OUT 64
#define HOPS 3

#define NPAD 100352                      // 98*1024, >= N_NODES
#define NTOT (2 * NPAD)                  // combined s|t dst-unit space = 200704
#define NBUCK 196                        // NTOT / 1024 buckets (1024 units each)
#define CAP 36864                        // fixed bucket capacity (mean 32768, +22 sigma)
#define RPS 1028                         // rowptr stride per bucket (1024 starts + end slot)
#define EPB 2048                         // edges per block in CSR-build passes

typedef unsigned short ushort_t;

__device__ __forceinline__ float bf2f(ushort_t u) {
    return __uint_as_float(((unsigned)u) << 16);
}
__device__ __forceinline__ float bflo(unsigned u) { return __uint_as_float(u << 16); }
__device__ __forceinline__ float bfhi(unsigned u) { return __uint_as_float(u & 0xffff0000u); }
__device__ __forceinline__ unsigned pack_bf16(float a, float b) {
    unsigned ua = __float_as_uint(a);
    unsigned ub = __float_as_uint(b);
    ua += 0x7fffu + ((ua >> 16) & 1u);
    ub += 0x7fffu + ((ub >> 16) & 1u);
    return (ua >> 16) | (ub & 0xffff0000u);
}

// ---------------- weight fold: Wc = W_{src,tgt} @ Wn_half ; bc = b @ Wn_half
__global__ __launch_bounds__(64) void wcomb_k(
    const float* __restrict__ Wsrc, const float* __restrict__ Wtgt,
    const float* __restrict__ bsrc, const float* __restrict__ btgt,
    const float* __restrict__ Wn,     // [2*HID, OUT]
    float* __restrict__ Wc,           // [512, 64]
    float* __restrict__ bc)           // [128]
{
    const int blk = blockIdx.x;
    const int j = threadIdx.x;
    if (blk < 512) {
        const float* Wsel = (blk < 256) ? Wsrc : Wtgt;
        const int i = blk & 255;
        const int koff = (blk < 256) ? 0 : HID;
        float acc = 0.f;
        for (int k = 0; k < HID; ++k)
            acc = fmaf(Wsel[i * HID + k], Wn[(koff + k) * OUT + j], acc);
        Wc[blk * OUT + j] = acc;
    } else {
        const float* bsel = (blk == 512) ? bsrc : btgt;
        const int koff = (blk == 512) ? 0 : HID;
        float acc = 0.f;
        for (int k = 0; k < HID; ++k)
            acc = fmaf(bsel[k], Wn[(koff + k) * OUT + j], acc);
        bc[(blk - 512) * OUT + j] = acc;
    }
}

// ---------------- input GEMM: h0 = bf16(X @ Wc + bc) ------------------------
__global__ __launch_bounds__(256) void gemm_in(
    const float* __restrict__ X,      // [N, FEAT]
    const float* __restrict__ B,      // [FEAT, OUT] folded weights
    const float* __restrict__ bias,   // [OUT] folded bias
    ushort_t* __restrict__ h0)        // [N, OUT] bf16
{
    __shared__ __align__(16) float at[64][76];   // A transposed [kk][row]
    __shared__ __align__(16) float bs[64][OUT];  // B chunk [kk][j]
    const int tid = threadIdx.x;
    const int tx = tid & 15;          // cols tx*4 .. tx*4+3
    const int ty = tid >> 4;          // rows ty*4 .. ty*4+3
    const int row0 = blockIdx.x * 64;

    float acc[4][4];
#pragma unroll
    for (int r = 0; r < 4; ++r)
#pragma unroll
        for (int c = 0; c < 4; ++c) acc[r][c] = 0.f;

    for (int chunk = 0; chunk < 4; ++chunk) {
        const int kbase = chunk * 64;
        {
            int lc = tid & 15, lr = tid >> 4;
#pragma unroll
            for (int p = 0; p < 4; ++p) {
                int r = lr + p * 16;
                int grow = row0 + r; if (grow > N_NODES - 1) grow = N_NODES - 1;
                float4 v = *(const float4*)(X + (size_t)grow * FEAT + kbase + lc * 4);
                float vv[4] = {v.x, v.y, v.z, v.w};
#pragma unroll
                for (int i = 0; i < 4; ++i) {
                    int ii = (i + lc) & 3;       // rotate to spread banks
                    at[lc * 4 + ii][r] = vv[ii];
                }
            }
        }
        {
            int jf = tid & 15, kk0 = tid >> 4;
#pragma unroll
            for (int p = 0; p < 4; ++p) {
                int kk = kk0 + p * 16;
                *(float4*)&bs[kk][jf * 4] =
                    *(const float4*)(B + (size_t)(kbase + kk) * OUT + jf * 4);
            }
        }
        __syncthreads();
#pragma unroll 8
        for (int kk = 0; kk < 64; ++kk) {
            float4 a = *(const float4*)&at[kk][ty * 4];
            float4 b = *(const float4*)&bs[kk][tx * 4];
            float av[4] = {a.x, a.y, a.z, a.w};
            float bv[4] = {b.x, b.y, b.z, b.w};
#pragma unroll
            for (int r = 0; r < 4; ++r)
#pragma unroll
                for (int c = 0; c < 4; ++c)
                    acc[r][c] = fmaf(av[r], bv[c], acc[r][c]);
        }
        __syncthreads();
    }

    float4 bj = *(const float4*)(bias + tx * 4);
    float bjv[4] = {bj.x, bj.y, bj.z, bj.w};
#pragma unroll
    for (int r = 0; r < 4; ++r) {
        int grow = row0 + ty * 4 + r;
        if (grow < N_NODES) {
            float o[4];
#pragma unroll
            for (int c = 0; c < 4; ++c) o[c] = acc[r][c] + bjv[c];
            size_t off = (size_t)grow * OUT + tx * 4;
            *(uint2*)(h0 + off) = make_uint2(pack_bf16(o[0], o[1]), pack_bf16(o[2], o[3]));
        }
    }
}

// ---------------- init per-bucket allocator cursors -------------------------
__global__ __launch_bounds__(256) void init_k(int* __restrict__ bcur) {
    int t = threadIdx.x;
    if (t < NBUCK) bcur[t] = t * CAP;
}

// ---------------- CSR build pass 1: multisplit scatter into buckets ---------
// entry: .x = src(17b) | dstlow(10b)<<17 ; .y = weight bits
__global__ __launch_bounds__(256) void fill_p1(
    const int* __restrict__ erow, const int* __restrict__ ecol,
    const float* __restrict__ ew,
    int* __restrict__ bcur, int2* __restrict__ meta_tmp)
{
    __shared__ int2 stage[2 * EPB];
    __shared__ unsigned char bkt[2 * EPB];
    __shared__ int lcnt[256], loff[256], gbase[256], cur[256];
    __shared__ int sdata[256];
    const int tid = threadIdx.x;
    const int base = blockIdx.x * EPB;
    const int n = min(EPB, N_EDGES - base);

    int r[8], c[8], wb[8];
    lcnt[tid] = 0;
    __syncthreads();
#pragma unroll
    for (int k = 0; k < 8; ++k) {
        int i = k * 256 + tid;
        if (i < n) {
            int e = base + i;
            r[k] = erow[e];
            c[k] = ecol[e];
            wb[k] = __float_as_int(ew[e]);
            atomicAdd(&lcnt[r[k] >> 10], 1);
            atomicAdd(&lcnt[(NPAD + c[k]) >> 10], 1);
        } else {
            r[k] = -1;
        }
    }
    __syncthreads();
    sdata[tid] = lcnt[tid];
    __syncthreads();
    for (int off = 1; off < 256; off <<= 1) {
        int t = (tid >= off) ? sdata[tid - off] : 0;
        __syncthreads();
        sdata[tid] += t;
        __syncthreads();
    }
    loff[tid] = sdata[tid] - lcnt[tid];
    cur[tid] = loff[tid];
    gbase[tid] = (lcnt[tid] > 0) ? atomicAdd(&bcur[tid], lcnt[tid]) : 0;
    __syncthreads();
#pragma unroll
    for (int k = 0; k < 8; ++k) {
        if (r[k] >= 0) {
            int bs_ = r[k] >> 10;
            int l = atomicAdd(&cur[bs_], 1);
            stage[l] = make_int2(c[k] | ((r[k] & 1023) << 17), wb[k]);
            bkt[l] = (unsigned char)bs_;
            int ut = NPAD + c[k];
            int bt_ = ut >> 10;
            int l2 = atomicAdd(&cur[bt_], 1);
            stage[l2] = make_int2(r[k] | ((ut & 1023) << 17), wb[k]);
            bkt[l2] = (unsigned char)bt_;
        }
    }
    __syncthreads();
    const int tot = 2 * n;
    for (int i = tid; i < tot; i += 256) {
        int b = bkt[i];
        meta_tmp[(size_t)gbase[b] + (i - loff[b])] = stage[i];
    }
}

// ---------------- CSR build pass 2: within-bucket sort + rowptr -------------
// meta uses the SAME sparse per-bucket segments [b*CAP, bcur[b]) as meta_tmp
// (round-6 crash root cause: meta was sized compact while positions were
//  sparse -> cross-bucket races -> unwritten poison holes -> wild gathers)
__global__ __launch_bounds__(256) void fill_p2(
    const int* __restrict__ bcur,
    const int2* __restrict__ meta_tmp,
    int2* __restrict__ meta, int* __restrict__ rowptr)
{
    __shared__ int cnt[1024];
    __shared__ int sdata[256];
    const int tid = threadIdx.x;
    const int b = blockIdx.x;
    const int seg0 = b * CAP;
    const int seg1 = bcur[b];

    for (int i = tid; i < 1024; i += 256) cnt[i] = 0;
    __syncthreads();
    for (int j = seg0 + tid; j < seg1; j += 256) {
        int2 e = meta_tmp[j];
        atomicAdd(&cnt[(e.x >> 17) & 1023], 1);
    }
    __syncthreads();
    int4 v = *(int4*)&cnt[tid * 4];
    int tsum = v.x + v.y + v.z + v.w;
    sdata[tid] = tsum;
    __syncthreads();
    for (int off = 1; off < 256; off <<= 1) {
        int t = (tid >= off) ? sdata[tid - off] : 0;
        __syncthreads();
        sdata[tid] += t;
        __syncthreads();
    }
    int excl = sdata[tid] - tsum;
    int4 o;
    o.x = seg0 + excl;
    o.y = o.x + v.x;
    o.z = o.y + v.y;
    o.w = o.z + v.z;
    *(int4*)(rowptr + b * RPS + tid * 4) = o;    // row starts (absolute into meta)
    *(int4*)&cnt[tid * 4] = o;                   // cursors
    if (tid == 0) rowptr[b * RPS + 1024] = seg1; // bucket end slot
    __syncthreads();
    for (int j = seg0 + tid; j < seg1; j += 256) {
        int2 e = meta_tmp[j];
        int pos = atomicAdd(&cnt[(e.x >> 17) & 1023], 1);
        meta[pos] = make_int2(e.x & 0x1ffff, e.y);
    }
}

// ---------------- pure SPMM: quarter-wave per edge, bf16, 64 cols ----------
// lane = (q: edge slot 0..3) * 16 + (sl: col group 0..15); 4 edges per wave-iter
__global__ __launch_bounds__(256) void spmm_k(
    const int* __restrict__ rowptr,
    const int2* __restrict__ meta,
    const ushort_t* __restrict__ xs, const ushort_t* __restrict__ xt,
    ushort_t* __restrict__ ns, ushort_t* __restrict__ nt)
{
    const int unit = blockIdx.x * 4 + (threadIdx.x >> 6);   // one wave per unit
    const int lane = threadIdx.x & 63;
    const int q  = lane >> 4;
    const int sl = lane & 15;

    const ushort_t* x; ushort_t* nxt;
    int node;
    if (unit < NPAD) {
        node = unit;
        if (node >= N_NODES) return;
        x = xs; nxt = ns;
    } else {
        node = unit - NPAD;
        if (node >= N_NODES) return;
        x = xt; nxt = nt;
    }

    const int rbase = (unit >> 10) * RPS + (unit & 1023);
    const int start = rowptr[rbase];
    const int end   = rowptr[rbase + 1];

    float a0 = 0.f, a1 = 0.f, a2 = 0.f, a3 = 0.f;
    const int coff = sl * 4;

    int jb = start;
    for (; jb + 7 < end; jb += 8) {          // 8 edges per iter, unmasked
        int2 mA = meta[jb + q];
        int2 mB = meta[jb + 4 + q];
        int sA = mA.x & 0x1ffff;             // insurance: bound the gather
        int sB = mB.x & 0x1ffff;
        uint2 uA = *(const uint2*)(x + ((size_t)sA << 6) + coff);
        uint2 uB = *(const uint2*)(x + ((size_t)sB << 6) + coff);
        float wA = __int_as_float(mA.y);
        float wB = __int_as_float(mB.y);
        a0 = fmaf(wA, bflo(uA.x), a0);
        a1 = fmaf(wA, bfhi(uA.x), a1);
        a2 = fmaf(wA, bflo(uA.y), a2);
        a3 = fmaf(wA, bfhi(uA.y), a3);
        a0 = fmaf(wB, bflo(uB.x), a0);
        a1 = fmaf(wB, bfhi(uB.x), a1);
        a2 = fmaf(wB, bflo(uB.y), a2);
        a3 = fmaf(wB, bfhi(uB.y), a3);
    }
    for (; jb < end; jb += 4) {              // masked tail groups
        int jj = jb + q;
        bool valid = jj < end;
        int2 m = meta[valid ? jj : start];
        int s = m.x & 0x1ffff;
        float w = valid ? __int_as_float(m.y) : 0.f;
        uint2 u = *(const uint2*)(x + ((size_t)s << 6) + coff);
        a0 = fmaf(w, bflo(u.x), a0);
        a1 = fmaf(w, bfhi(u.x), a1);
        a2 = fmaf(w, bflo(u.y), a2);
        a3 = fmaf(w, bfhi(u.y), a3);
    }

    // fold the 4 edge-slot partials (lanes differ in bits 4-5)
    a0 += __shfl_xor(a0, 16, 64);
    a1 += __shfl_xor(a1, 16, 64);
    a2 += __shfl_xor(a2, 16, 64);
    a3 += __shfl_xor(a3, 16, 64);
    a0 += __shfl_xor(a0, 32, 64);
    a1 += __shfl_xor(a1, 32, 64);
    a2 += __shfl_xor(a2, 32, 64);
    a3 += __shfl_xor(a3, 32, 64);

    if (q == 0) {
        *(uint2*)(nxt + ((size_t)node << 6) + coff) =
            make_uint2(pack_bf16(a0, a1), pack_bf16(a2, a3));
    }
}

// ---------------- combine: out = Σ ws[h]·hs_h + Σ wt[h]·ht_h + bn ----------
__global__ __launch_bounds__(256) void combine_k(
    const ushort_t* __restrict__ s0, const ushort_t* __restrict__ s1,
    const ushort_t* __restrict__ s2, const ushort_t* __restrict__ s3,
    const ushort_t* __restrict__ t0, const ushort_t* __restrict__ t1,
    const ushort_t* __restrict__ t2, const ushort_t* __restrict__ t3,
    const float* __restrict__ wsv, const float* __restrict__ wtv,
    const float* __restrict__ bn,
    float* __restrict__ out)
{
    const int gid = blockIdx.x * 256 + threadIdx.x;   // one per 4 cols
    if (gid >= N_NODES * (OUT / 4)) return;
    const size_t off = (size_t)gid * 4;

    float4 b = ((const float4*)bn)[gid & (OUT / 4 - 1)];
    float acc[4] = {b.x, b.y, b.z, b.w};

    const ushort_t* bufs[8] = {s0, s1, s2, s3, t0, t1, t2, t3};
    float w[8];
#pragma unroll
    for (int h = 0; h < 4; ++h) { w[h] = wsv[h]; w[4 + h] = wtv[h]; }

#pragma unroll
    for (int h = 0; h < 8; ++h) {
        ushort4 u = *(const ushort4*)(bufs[h] + off);
        acc[0] = fmaf(w[h], bf2f(u.x), acc[0]);
        acc[1] = fmaf(w[h], bf2f(u.y), acc[1]);
        acc[2] = fmaf(w[h], bf2f(u.z), acc[2]);
        acc[3] = fmaf(w[h], bf2f(u.w), acc[3]);
    }
    *(float4*)(out + off) = make_float4(acc[0], acc[1], acc[2], acc[3]);
}

extern "C" void kernel_launch(void* const* d_in, const int* in_sizes, int n_in,
                              void* d_out, int out_size, void* d_ws, size_t ws_size,
                              hipStream_t stream) {
    const float* fsrc = (const float*)d_in[0];
    const float* ftgt = (const float*)d_in[1];
    const int*   erow = (const int*)d_in[2];
    const int*   ecol = (const int*)d_in[3];
    const float* ew   = (const float*)d_in[4];
    const float* Wsrc = (const float*)d_in[5];
    const float* bsrc = (const float*)d_in[6];
    const float* Wtgt = (const float*)d_in[7];
    const float* btgt = (const float*)d_in[8];
    const float* ws   = (const float*)d_in[9];
    const float* wt   = (const float*)d_in[10];
    const float* Wn   = (const float*)d_in[11];
    const float* bn   = (const float*)d_in[12];
    float* out = (float*)d_out;

    const size_t buf = (size_t)N_NODES * OUT;   // elements per hop buffer (64-dim)
    char* p = (char*)d_ws;
    ushort_t* hs[4]; ushort_t* ht[4];
    for (int h = 0; h < 4; ++h) {
        hs[h] = (ushort_t*)p; p += buf * 2;
        ht[h] = (ushort_t*)p; p += buf * 2;
    }
    int2* meta     = (int2*)p;  p += (size_t)NBUCK * CAP * 8;   // sparse layout!
    int2* meta_tmp = (int2*)p;  p += (size_t)NBUCK * CAP * 8;
    int* rowptr    = (int*)p;   p += (size_t)NBUCK * RPS * 4 + 64;
    float* Wc      = (float*)p; p += 512 * OUT * 4;
    float* bc      = (float*)p; p += 128 * 4;
    int* bcur      = (int*)p;   p += 256 * 4;

    const int eblocks = (N_EDGES + EPB - 1) / EPB;   // 1563
    const int gblocks = (N_NODES + 63) / 64;         // 1563

    // fold output projection into input weights
    wcomb_k<<<514, 64, 0, stream>>>(Wsrc, Wtgt, bsrc, btgt, Wn, Wc, bc);

    // input GEMMs -> bf16 hop-0 buffers (already projected to 64 dims)
    gemm_in<<<gblocks, 256, 0, stream>>>(fsrc, Wc, bc, hs[0]);
    gemm_in<<<gblocks, 256, 0, stream>>>(ftgt, Wc + 256 * OUT, bc + OUT, ht[0]);

    // CSR build: fixed-capacity buckets (no counting pre-pass)
    init_k<<<1, 256, 0, stream>>>(bcur);
    fill_p1<<<eblocks, 256, 0, stream>>>(erow, ecol, ew, bcur, meta_tmp);
    fill_p2<<<NBUCK, 256, 0, stream>>>(bcur, meta_tmp, meta, rowptr);

    // 3 hops, both directions per launch
    const int sblocks = NTOT / 4;
    for (int h = 1; h <= HOPS; ++h) {
        spmm_k<<<sblocks, 256, 0, stream>>>(rowptr, meta,
                                            hs[h - 1], ht[h - 1], hs[h], ht[h]);
    }

    // final weighted combine + bias
    combine_k<<<(N_NODES * (OUT / 4) + 255) / 256, 256, 0, stream>>>(
        hs[0], hs[1], hs[2], hs[3], ht[0], ht[1], ht[2], ht[3], ws, wt, bn, out);
}